// Round 1
// 341.379 us; speedup vs baseline: 1.0171x; 1.0171x over previous
//
#include <hip/hip_runtime.h>

#define S_DIM 256
#define N_HM 32
#define K_APP 16
#define HW (S_DIM * S_DIM)

// ---------------------------------------------------------------------------
// Kernel 1: one block (256 thr = 4 INDEPENDENT waves) per (b, h).
// No LDS, no barriers. Wave wid owns heatmap rows n = wid*8 .. wid*8+7.
// Per row: register softmax over w (64-lane shfl reduce), then per-lane
// partial dots A[k] = sum_{4 w's} e_w * x[k][w]; a split-butterfly reduce
// (16 values x 64 lanes -> lane holds k = lane&15) finishes the row-dot.
// ---------------------------------------------------------------------------
template <bool ATOMIC>
__global__ __launch_bounds__(256, 4) void k1_softmax_pool(
    const float* __restrict__ x,     // [B,16,256,256]
    const float* __restrict__ raw,   // [B,32,256,256]
    float* __restrict__ outp)        // partial [4096][512] or av [B][512]
{
    const int tid  = threadIdx.x;
    const int b    = blockIdx.x >> 8;
    const int h    = blockIdx.x & 255;
    const int wid  = tid >> 6;
    const int lane = tid & 63;

    // x fragments: xv[k] = x[b][k][h][4*lane .. 4*lane+3]
    // (16 KB per block; all 4 waves read the same lines -> L1-resident)
    const float* xb = x + ((size_t)(b * K_APP) << 16) + (h << 8) + (lane << 2);
    float4 xv[K_APP];
    #pragma unroll
    for (int k = 0; k < K_APP; ++k)
        xv[k] = *(const float4*)(xb + ((size_t)k << 16));

    const float* rb = raw + ((size_t)(b * N_HM) << 16) + (h << 8) + (lane << 2);

    // one-row-ahead prefetch; 16 waves/CU provide the rest of the hiding
    float4 nxt = *(const float4*)(rb + ((size_t)(wid * 8) << 16));

    #pragma unroll
    for (int i = 0; i < 8; ++i) {
        const int n = wid * 8 + i;
        float4 cur = nxt;
        if (i < 7) nxt = *(const float4*)(rb + ((size_t)(n + 1) << 16));

        // ---- softmax over the 256-wide row (unnormalized e, fold 1/s late) ----
        float m = fmaxf(fmaxf(cur.x, cur.y), fmaxf(cur.z, cur.w));
        #pragma unroll
        for (int off = 32; off > 0; off >>= 1) m = fmaxf(m, __shfl_xor(m, off));
        float e0 = __expf(cur.x - m), e1 = __expf(cur.y - m);
        float e2 = __expf(cur.z - m), e3 = __expf(cur.w - m);
        float s = e0 + e1 + e2 + e3;
        #pragma unroll
        for (int off = 32; off > 0; off >>= 1) s += __shfl_xor(s, off);
        const float inv = 1.0f / s;

        // ---- pool: per-lane partial dot for all 16 k ----
        float A[16];
        #pragma unroll
        for (int k = 0; k < K_APP; ++k)
            A[k] = e0 * xv[k].x + e1 * xv[k].y + e2 * xv[k].z + e3 * xv[k].w;

        // ---- split-butterfly: each step halves values/lane (17 shfl total) ----
        #pragma unroll
        for (int j = 0; j < 8; ++j) {
            float send = (lane & 8) ? A[j] : A[j + 8];
            float keep = (lane & 8) ? A[j + 8] : A[j];
            A[j] = keep + __shfl_xor(send, 8);
        }
        #pragma unroll
        for (int j = 0; j < 4; ++j) {
            float send = (lane & 4) ? A[j] : A[j + 4];
            float keep = (lane & 4) ? A[j + 4] : A[j];
            A[j] = keep + __shfl_xor(send, 4);
        }
        #pragma unroll
        for (int j = 0; j < 2; ++j) {
            float send = (lane & 2) ? A[j] : A[j + 2];
            float keep = (lane & 2) ? A[j + 2] : A[j];
            A[j] = keep + __shfl_xor(send, 2);
        }
        {
            float send = (lane & 1) ? A[0] : A[1];
            float keep = (lane & 1) ? A[1] : A[0];
            A[0] = keep + __shfl_xor(send, 1);
        }
        // A[0]: k = lane&15, summed over this lane's 16-lane quarter
        float v = A[0];
        v += __shfl_xor(v, 16);
        v += __shfl_xor(v, 32);
        v *= inv;

        if (ATOMIC) {
            if (lane < 16)
                atomicAdd(outp + (b << 9) + (n << 4) + lane, v);
        } else {
            if (lane < 16)
                outp[((size_t)blockIdx.x << 9) + (n << 4) + lane] = v;
        }
    }
}

// ---------------------------------------------------------------------------
// Kernel 1b: reduce 256 h-partials -> av[b][n][k].
// 256 blocks; each block owns 32 outputs; h split into 8 chunks of 32 across
// the block (coalesced column reads), LDS tree for the final factor 8.
// ---------------------------------------------------------------------------
__global__ __launch_bounds__(256) void k1_reduce(
    const float* __restrict__ partial, float* __restrict__ av)
{
    __shared__ float s_lds[256];
    const int tid = threadIdx.x;
    const int o   = (blockIdx.x << 5) + (tid & 31);   // output index 0..8191
    const int ch  = tid >> 5;                          // h-chunk 0..7
    const int b   = o >> 9;
    const int r   = o & 511;

    const float* p = partial + ((size_t)((b << 8) + (ch << 5)) << 9) + r;
    float s = 0.0f;
    #pragma unroll 8
    for (int j = 0; j < 32; ++j) s += p[(size_t)j << 9];

    s_lds[tid] = s;
    __syncthreads();
    if (tid < 32) {
        float t = s_lds[tid];
        #pragma unroll
        for (int c = 1; c < 8; ++c) t += s_lds[tid + (c << 5)];
        av[o] = t;
    }
}

// ---------------------------------------------------------------------------
// Kernel 2: out[b,k,h,w] = (sum_n fit[b,n,h,w]*av[b,n,k]) / (1+sum_n fit)
// float2 per thread (8 B/lane loads & stores), av via uniform scalar loads.
// ---------------------------------------------------------------------------
__global__ __launch_bounds__(256, 4) void k2_combine(
    const float* __restrict__ fit,   // [B,32,256,256]
    const float* __restrict__ av,    // [B,32,16]
    float* __restrict__ out)         // [B,16,256,256]
{
    const int tid = threadIdx.x;
    const int b   = blockIdx.x >> 7;                   // 128 blocks per b
    const int hw2 = ((blockIdx.x & 127) << 8) + tid;   // float2 index in [0,32768)

    const float*  avb = av + (b << 9);                 // block-uniform
    const float2* fb  = (const float2*)fit + ((size_t)(b * N_HM) << 15) + hw2;

    float2 num[16];
    #pragma unroll
    for (int k = 0; k < 16; ++k) num[k] = make_float2(0.0f, 0.0f);
    float dx = 1.0f, dy = 1.0f;

    #pragma unroll 8
    for (int n = 0; n < N_HM; ++n) {
        float2 f = fb[(size_t)n << 15];
        dx += f.x; dy += f.y;
        const float4* ar = (const float4*)(avb + (n << 4)); // uniform -> s_load
        float4 a0 = ar[0], a1 = ar[1], a2 = ar[2], a3 = ar[3];
        num[0].x  += f.x * a0.x;  num[0].y  += f.y * a0.x;
        num[1].x  += f.x * a0.y;  num[1].y  += f.y * a0.y;
        num[2].x  += f.x * a0.z;  num[2].y  += f.y * a0.z;
        num[3].x  += f.x * a0.w;  num[3].y  += f.y * a0.w;
        num[4].x  += f.x * a1.x;  num[4].y  += f.y * a1.x;
        num[5].x  += f.x * a1.y;  num[5].y  += f.y * a1.y;
        num[6].x  += f.x * a1.z;  num[6].y  += f.y * a1.z;
        num[7].x  += f.x * a1.w;  num[7].y  += f.y * a1.w;
        num[8].x  += f.x * a2.x;  num[8].y  += f.y * a2.x;
        num[9].x  += f.x * a2.y;  num[9].y  += f.y * a2.y;
        num[10].x += f.x * a2.z;  num[10].y += f.y * a2.z;
        num[11].x += f.x * a2.w;  num[11].y += f.y * a2.w;
        num[12].x += f.x * a3.x;  num[12].y += f.y * a3.x;
        num[13].x += f.x * a3.y;  num[13].y += f.y * a3.y;
        num[14].x += f.x * a3.z;  num[14].y += f.y * a3.z;
        num[15].x += f.x * a3.w;  num[15].y += f.y * a3.w;
    }

    const float ix = 1.0f / dx, iy = 1.0f / dy;
    float2* ob = (float2*)out + ((size_t)(b * K_APP) << 15) + hw2;
    #pragma unroll
    for (int k = 0; k < 16; ++k)
        ob[(size_t)k << 15] = make_float2(num[k].x * ix, num[k].y * iy);
}

// ---------------------------------------------------------------------------
extern "C" void kernel_launch(void* const* d_in, const int* in_sizes, int n_in,
                              void* d_out, int out_size, void* d_ws, size_t ws_size,
                              hipStream_t stream)
{
    const float* x   = (const float*)d_in[0];   // [16,16,256,256]
    const float* raw = (const float*)d_in[1];   // [16,32,256,256]
    const float* fit = (const float*)d_in[2];   // [16,32,256,256]
    float* out = (float*)d_out;

    float* av      = (float*)d_ws;              // 8192 floats (32 KB)
    float* partial = (float*)d_ws + 8192;       // 4096*512 floats (8 MB)
    const size_t need = (size_t)(8192 + 4096 * 512) * sizeof(float);

    if (ws_size >= need) {
        k1_softmax_pool<false><<<4096, 256, 0, stream>>>(x, raw, partial);
        k1_reduce<<<256, 256, 0, stream>>>(partial, av);
    } else {
        hipMemsetAsync(av, 0, 8192 * sizeof(float), stream);
        k1_softmax_pool<true><<<4096, 256, 0, stream>>>(x, raw, av);
    }
    k2_combine<<<2048, 256, 0, stream>>>(fit, av, out);
}